// Round 14
// baseline (401.557 us; speedup 1.0000x reference)
//
#include <hip/hip_runtime.h>
#include <cstdint>
#include <cstddef>

// dims
#define G_    16
#define A_    64
#define P_    32
#define DIN_  768
#define DEMB_ 384
#define HP_   256
#define HA_   128
#define GA_   1024
#define N1_   1024
#define N2_   512
#define TCH   16          // timesteps per chunk

typedef float    f32x4   __attribute__((ext_vector_type(4)));
typedef _Float16 half8_t __attribute__((ext_vector_type(8)));
typedef _Float16 half4_t __attribute__((ext_vector_type(4)));

__device__ __forceinline__ float sigmoidf_(float x) { return 1.0f / (1.0f + __expf(-x)); }
__device__ __forceinline__ float tanhf_(float x) { return 2.0f / (1.0f + __expf(-2.0f * x)) - 1.0f; }
__device__ __forceinline__ _Float16 us2h(unsigned short u) { _Float16 h; __builtin_memcpy(&h, &u, 2); return h; }
__device__ __forceinline__ unsigned short h2us(_Float16 h) { unsigned short u; __builtin_memcpy(&u, &h, 2); return u; }

// ---------------- prep kernels ----------------

__global__ __launch_bounds__(256) void k_wk(const float* __restrict__ w_embed,
                                            const float* __restrict__ k_post,
                                            float* __restrict__ Bmat) {
    int j  = blockIdx.x * 256 + threadIdx.x;
    int k0 = blockIdx.y * 4;
    float acc0 = 0.f, acc1 = 0.f, acc2 = 0.f, acc3 = 0.f;
    for (int d = 0; d < DEMB_; ++d) {
        float kp = k_post[(size_t)d * N1_ + j];
        acc0 += w_embed[(size_t)(k0 + 0) * DEMB_ + d] * kp;
        acc1 += w_embed[(size_t)(k0 + 1) * DEMB_ + d] * kp;
        acc2 += w_embed[(size_t)(k0 + 2) * DEMB_ + d] * kp;
        acc3 += w_embed[(size_t)(k0 + 3) * DEMB_ + d] * kp;
    }
    Bmat[(size_t)(k0 + 0) * N1_ + j] = acc0;
    Bmat[(size_t)(k0 + 1) * N1_ + j] = acc1;
    Bmat[(size_t)(k0 + 2) * N1_ + j] = acc2;
    Bmat[(size_t)(k0 + 3) * N1_ + j] = acc3;
}

__global__ __launch_bounds__(256) void k_bias_p(const float* __restrict__ b_embed,
                                                const float* __restrict__ k_post,
                                                const float* __restrict__ b_post,
                                                float* __restrict__ biasZp) {
    int p = blockIdx.x * 256 + threadIdx.x;
    int n = (p >> 6) * 16 + (p & 15) + 256 * ((p >> 4) & 3);
    float acc = b_post[n];
    for (int d = 0; d < DEMB_; ++d)
        acc += b_embed[d] * k_post[(size_t)d * N1_ + n];
    biasZp[p] = acc;
}

__global__ __launch_bounds__(256) void k_t16(const float* __restrict__ Bmat,
                                             _Float16* __restrict__ Bt16) {
    __shared__ float tile[64][65];
    const int tid = threadIdx.x;
    const int p0 = blockIdx.x * 64;
    const int k0 = blockIdx.y * 64;
    const int jgrp = p0 >> 6;
#pragma unroll
    for (int i = 0; i < 16; ++i) {
        int idx = i * 256 + tid;
        int pp = idx & 63, kk = idx >> 6;
        int n = jgrp * 16 + (pp & 15) + 256 * ((pp >> 4) & 3);
        tile[pp][kk] = Bmat[(size_t)(k0 + kk) * N1_ + n];
    }
    __syncthreads();
    const int pp = tid >> 2;
    const int kq = (tid & 3) * 16;
    _Float16 buf[16];
#pragma unroll
    for (int i = 0; i < 16; ++i) buf[i] = (_Float16)tile[pp][kq + i];
    _Float16* dst = &Bt16[(size_t)(p0 + pp) * DIN_ + k0 + kq];
    *(half8_t*)dst       = *(half8_t*)&buf[0];
    *(half8_t*)(dst + 8) = *(half8_t*)&buf[8];
}

__global__ __launch_bounds__(256) void k_bfrag(const float* __restrict__ r_post,
                                               _Float16* __restrict__ Bfrag) {
    int idx = blockIdx.x * 256 + threadIdx.x;   // 0..32767
    int pt = idx >> 9;
    int kt = (idx >> 6) & 7;
    int l  = idx & 63;
    int p = pt * 16 + (l & 15);
    int n = (p >> 6) * 16 + (p & 15) + 256 * ((p >> 4) & 3);
    int kb = kt * 32 + (l >> 4) * 8;
    _Float16 buf[8];
#pragma unroll
    for (int s = 0; s < 8; ++s) buf[s] = (_Float16)r_post[(size_t)(kb + s) * N1_ + n];
    *(half8_t*)&Bfrag[(size_t)idx * 8] = *(half8_t*)buf;
}

// r_auth -> fragment-major fp16: Afrag[((wv*16 + q*4 + kt)*64 + lane)*8 + s]
//   = r_auth[kt*32 + (lane>>4)*8 + s][q*128 + wv*16 + (lane&15)]
__global__ __launch_bounds__(256) void k_afrag(const float* __restrict__ r_auth,
                                               _Float16* __restrict__ Afrag) {
    int idx = blockIdx.x * 256 + threadIdx.x;   // 0..8191
    int unit = idx >> 6;                        // 0..127
    int lane = idx & 63;
    int wv = unit >> 4, q = (unit >> 2) & 3, kt = unit & 3;
    int n = q * 128 + wv * 16 + (lane & 15);
    int kb = kt * 32 + (lane >> 4) * 8;
    _Float16 buf[8];
#pragma unroll
    for (int s = 0; s < 8; ++s) buf[s] = (_Float16)r_auth[(size_t)(kb + s) * N2_ + n];
    *(half8_t*)&Afrag[(size_t)idx * 8] = *(half8_t*)buf;
}

// ---------------- shared-memory structs ----------------
#define ZBM 128
#define ZBN 256
#define ZBK 32
#define ZPAD 40

struct ZgLDS {
    union {
        struct { _Float16 As[ZBM][ZPAD]; _Float16 Bs[ZBN][ZPAD]; } S;
        _Float16 Hs[64][264];
    } u;
};
struct RecLDS {
    _Float16 wlds[16 * 8 * 64 * 8];   // 128 KB
    _Float16 hbuf[2][4096];           // 16 KB
};

// ---------------- zgemm core: 1024 threads, 128x256 tile ----------------
__device__ __forceinline__ void zgemm_core(ZgLDS* L, int bid, int tid,
                                           const float* __restrict__ x,
                                           const _Float16* __restrict__ Bt16,
                                           const float* __restrict__ biasZp,
                                           _Float16* __restrict__ Zq, int tbase) {
    const int wg = (bid & 7) * 64 + (bid >> 3);   // XCD swizzle (512 % 8 == 0)
    const int bm = (wg & 127) * ZBM;
    const int bn = (wg >> 7) * ZBN;

    const int arow = tid >> 3, akq = (tid & 7) * 4;    // A: 128 rows x 8 quads(4 halfs)
    const int brow = tid >> 2, bkq = (tid & 3) * 8;    // B: 256 rows x 4 octs(8 halfs)
    const int lane = tid & 63, w = tid >> 6;           // w 0..15
    const int wm = (w >> 2) * 32, wn = (w & 3) * 64;
    const int frc = lane & 15, frk = (lane >> 4) * 8;

    const int crow = bm + arow;
    const size_t xrow = (size_t)(crow >> 4) * P_ + tbase + (crow & 15);
    const float*    aptr = &x[xrow * DIN_ + akq];
    const _Float16* bptr = &Bt16[(size_t)(bn + brow) * DIN_ + bkq];

    f32x4 acc[2][4];
#pragma unroll
    for (int i = 0; i < 2; ++i)
#pragma unroll
        for (int j = 0; j < 4; ++j) acc[i][j] = (f32x4)0.0f;

    float4 a0 = *(const float4*)aptr;
    uint4  b0 = *(const uint4*)bptr;

    const int NK = DIN_ / ZBK;   // 24
    for (int kt = 0; kt < NK; ++kt) {
        const int kn = (kt + 1 < NK) ? (kt + 1) * ZBK : kt * ZBK;
        float4 na0 = *(const float4*)(aptr + kn);
        uint4  nb0 = *(const uint4*)(bptr + kn);

        half4_t ahv;
        ahv[0] = (_Float16)a0.x; ahv[1] = (_Float16)a0.y;
        ahv[2] = (_Float16)a0.z; ahv[3] = (_Float16)a0.w;

        __syncthreads();
        *(half4_t*)&L->u.S.As[arow][akq] = ahv;
        *(uint4*)&L->u.S.Bs[brow][bkq]   = b0;
        __syncthreads();

        half8_t bf[4];
#pragma unroll
        for (int fn = 0; fn < 4; ++fn)
            bf[fn] = *(const half8_t*)&L->u.S.Bs[wn + fn * 16 + frc][frk];
#pragma unroll
        for (int fm = 0; fm < 2; ++fm) {
            half8_t aH = *(const half8_t*)&L->u.S.As[wm + fm * 16 + frc][frk];
#pragma unroll
            for (int fn = 0; fn < 4; ++fn)
                acc[fm][fn] = __builtin_amdgcn_mfma_f32_16x16x32_f16(aH, bf[fn], acc[fm][fn], 0, 0, 0);
        }
        a0 = na0; b0 = nb0;
    }

    float bzv[4];
#pragma unroll
    for (int fn = 0; fn < 4; ++fn) bzv[fn] = biasZp[bn + wn + fn * 16 + frc];

#pragma unroll
    for (int half_ = 0; half_ < 2; ++half_) {
        __syncthreads();
        if ((w >> 3) == half_) {
#pragma unroll
            for (int fm = 0; fm < 2; ++fm)
#pragma unroll
                for (int fn = 0; fn < 4; ++fn)
#pragma unroll
                    for (int r = 0; r < 4; ++r) {
                        int rl = ((w >> 2) & 1) * 32 + fm * 16 + (lane >> 4) * 4 + r;
                        int cl = wn + fn * 16 + frc;
                        int clp = ((cl >> 6) * 16 + (cl & 15)) * 4 + ((cl >> 4) & 3);
                        L->u.Hs[rl][clp] = (_Float16)(acc[fm][fn][r] + bzv[fn]);
                    }
        }
        __syncthreads();
        // write Zq2 layout: unit (tloc, hcl); 4 rows x 4 gates = 32B contiguous
        const int brb = (bm + half_ * 64) >> 4;
        const int rg  = brb >> 4;
        const int l4r = (brb & 15) >> 2;
        {
            int tloc = tid >> 6, hcl = tid & 63;
            _Float16 buf[16];
#pragma unroll
            for (int rr = 0; rr < 4; ++rr) {
                half4_t h4 = *(const half4_t*)&L->u.Hs[tloc + 16 * rr][hcl * 4];
                buf[rr * 4 + 0] = h4[0]; buf[rr * 4 + 1] = h4[1];
                buf[rr * 4 + 2] = h4[2]; buf[rr * 4 + 3] = h4[3];
            }
            int wvg  = (bn >> 6) + (hcl >> 4);
            int tid2 = wvg * 64 + l4r * 16 + (hcl & 15);
            _Float16* dst = &Zq[((size_t)(tloc * 64 + rg) * 1024 + tid2) * 16];
            *(uint4*)dst       = *(const uint4*)&buf[0];
            *(uint4*)(dst + 8) = *(const uint4*)&buf[8];
        }
    }
}

// ---------------- rec core: 1024 threads, 16 rows/block, weights 3/4 resident ----------------
__device__ __forceinline__ void rec_core(RecLDS* L, int blk, int tid,
                                         const _Float16* __restrict__ Zq,
                                         const _Float16* __restrict__ Bfrag,
                                         float* __restrict__ csave,
                                         unsigned short* __restrict__ hsave,
                                         float* __restrict__ hF32, int tbase) {
    const int lane = tid & 63, wv = tid >> 6;  // wv 0..15
    const int hl = lane & 15, l4 = lane >> 4;
    const int r0 = blk * 16;
    const int hc = wv * 16 + hl;

    half8_t wreg[16];
#pragma unroll
    for (int q = 0; q < 2; ++q)
#pragma unroll
        for (int kt = 0; kt < 8; ++kt)
            wreg[q * 8 + kt] = *(const half8_t*)&Bfrag[(((size_t)(4 * wv + q) * 8 + kt) * 64 + lane) * 8];
#pragma unroll
    for (int kt = 0; kt < 8; ++kt)
        *(half8_t*)&L->wlds[((wv * 8 + kt) * 64 + lane) * 8] =
            *(const half8_t*)&Bfrag[(((size_t)(4 * wv + 2) * 8 + kt) * 64 + lane) * 8];
    const _Float16* w3base = &Bfrag[((size_t)(4 * wv + 3) * 8 * 64 + lane) * 8];

    float cst[4];
    if (tbase == 0) {
#pragma unroll
        for (int i = 0; i < 4; ++i) cst[i] = 0.f;
    } else {
        f32x4 cv = *(const f32x4*)&csave[((size_t)blk * 1024 + tid) * 4];
#pragma unroll
        for (int i = 0; i < 4; ++i) cst[i] = cv[i];
#pragma unroll
        for (int rr = 0; rr < 4; ++rr) {
            int row = l4 * 4 + rr;
            int lidx = (((hc >> 5) * 64) + (((hc & 31) >> 3) * 16 + row)) * 8 + (hc & 7);
            L->hbuf[0][lidx] = us2h(hsave[((size_t)(r0 + row)) * HP_ + hc]);
        }
    }
    __syncthreads();

    const _Float16* zp0 = &Zq[((size_t)blk * 1024 + tid) * 16];
    half8_t z01N = *(const half8_t*)zp0;
    half8_t z23N = *(const half8_t*)(zp0 + 8);

    for (int tt = 0; tt < TCH; ++tt) {
        const int t = tbase + tt;
        const int cur = t & 1, nxt = cur ^ 1;

        half8_t z01 = z01N, z23 = z23N;
        if (tt + 1 < TCH) {
            const _Float16* zpn = zp0 + (size_t)(tt + 1) * 1048576;
            z01N = *(const half8_t*)zpn;
            z23N = *(const half8_t*)(zpn + 8);
        }

        f32x4 acc[4];
#pragma unroll
        for (int i = 0; i < 4; ++i) acc[i] = (f32x4)0.0f;

        if (t > 0) {
#pragma unroll
            for (int kt = 0; kt < 8; ++kt) {
                half8_t ah = *(const half8_t*)&L->hbuf[cur][(kt * 64 + lane) * 8];
                half8_t b2 = *(const half8_t*)&L->wlds[((wv * 8 + kt) * 64 + lane) * 8];
                half8_t w3 = *(const half8_t*)&w3base[(size_t)kt * 512];
                acc[0] = __builtin_amdgcn_mfma_f32_16x16x32_f16(ah, wreg[kt],     acc[0], 0, 0, 0);
                acc[1] = __builtin_amdgcn_mfma_f32_16x16x32_f16(ah, wreg[8 + kt], acc[1], 0, 0, 0);
                acc[2] = __builtin_amdgcn_mfma_f32_16x16x32_f16(ah, b2,           acc[2], 0, 0, 0);
                acc[3] = __builtin_amdgcn_mfma_f32_16x16x32_f16(ah, w3,           acc[3], 0, 0, 0);
            }
        }

        const bool last = (t == P_ - 1);
        const bool save = (tbase == 0) && (tt == TCH - 1);
#pragma unroll
        for (int rr = 0; rr < 4; ++rr) {
            const half8_t zsrc = (rr < 2) ? z01 : z23;
            const int o = (rr & 1) * 4;
            float gi = acc[0][rr] + (float)zsrc[o + 0];
            float gf = acc[1][rr] + (float)zsrc[o + 1];
            float gg = acc[2][rr] + (float)zsrc[o + 2];
            float go = acc[3][rr] + (float)zsrc[o + 3];
            float cn = sigmoidf_(gf) * cst[rr] + sigmoidf_(gi) * tanhf_(gg);
            cst[rr] = cn;
            float hv = sigmoidf_(go) * tanhf_(cn);
            int row = l4 * 4 + rr;
            int lidx = (((hc >> 5) * 64) + (((hc & 31) >> 3) * 16 + row)) * 8 + (hc & 7);
            _Float16 hh = (_Float16)hv;
            L->hbuf[nxt][lidx] = hh;
            if (save) hsave[((size_t)(r0 + row)) * HP_ + hc] = h2us(hh);
            if (last) hF32[(size_t)(r0 + row) * HP_ + hc] = hv;
        }
        __syncthreads();
    }

    if (tbase == 0) {
        f32x4 cv;
#pragma unroll
        for (int i = 0; i < 4; ++i) cv[i] = cst[i];
        *(f32x4*)&csave[((size_t)blk * 1024 + tid) * 4] = cv;
    }
}

// ---------------- standalone kernels + fused kernel ----------------
__global__ __launch_bounds__(1024, 4) void k_zgemm(const float* __restrict__ x,
                                                   const _Float16* __restrict__ Bt16,
                                                   const float* __restrict__ biasZp,
                                                   _Float16* __restrict__ Zq, int tbase) {
    __shared__ __align__(16) ZgLDS L;
    zgemm_core(&L, blockIdx.x, threadIdx.x, x, Bt16, biasZp, Zq, tbase);
}

__global__ __launch_bounds__(1024, 4) void k_rec(const _Float16* __restrict__ Zq,
                                                 const _Float16* __restrict__ Bfrag,
                                                 float* __restrict__ csave,
                                                 unsigned short* __restrict__ hsave,
                                                 float* __restrict__ hF32, int tbase) {
    __shared__ __align__(16) RecLDS L;
    rec_core(&L, blockIdx.x, threadIdx.x, Zq, Bfrag, csave, hsave, hF32, tbase);
}

// fused: blocks 0..63 = rec(chunk0 from Zq0), blocks 64..575 = zgemm(chunk1 -> Zq1)
__global__ __launch_bounds__(1024, 4) void k_fuse(const float* __restrict__ x,
                                                  const _Float16* __restrict__ Bt16,
                                                  const float* __restrict__ biasZp,
                                                  const _Float16* __restrict__ Zq0,
                                                  _Float16* __restrict__ Zq1,
                                                  const _Float16* __restrict__ Bfrag,
                                                  float* __restrict__ csave,
                                                  unsigned short* __restrict__ hsave,
                                                  float* __restrict__ hF32) {
    __shared__ __align__(16) union { RecLDS r; ZgLDS z; } L;
    if (blockIdx.x < 64)
        rec_core(&L.r, blockIdx.x, threadIdx.x, Zq0, Bfrag, csave, hsave, hF32, 0);
    else
        zgemm_core(&L.z, blockIdx.x - 64, threadIdx.x, x, Bt16, biasZp, Zq1, TCH);
}

// ---------------- author stage ----------------
// z2 layout (f32): [a][tid2*16 + rr*4 + q], tid2 = (hcol>>4)*64 + (g>>2)*16 + (hcol&15)
__global__ __launch_bounds__(256) void k_zauth(const float* __restrict__ h,
                                               const float* __restrict__ k_auth,
                                               const float* __restrict__ b_auth,
                                               float* __restrict__ z2) {
    const int j = blockIdx.x * 256 + threadIdx.x;   // gate col 0..511
    const int r0 = blockIdx.y * 4;
    float acc0 = b_auth[j], acc1 = acc0, acc2 = acc0, acc3 = acc0;
    for (int k = 0; k < HP_; ++k) {
        const float kp = k_auth[(size_t)k * N2_ + j];
        acc0 += h[(size_t)(r0 + 0) * HP_ + k] * kp;
        acc1 += h[(size_t)(r0 + 1) * HP_ + k] * kp;
        acc2 += h[(size_t)(r0 + 2) * HP_ + k] * kp;
        acc3 += h[(size_t)(r0 + 3) * HP_ + k] * kp;
    }
    const int q = j >> 7, hcol = j & 127;
#pragma unroll
    for (int r = 0; r < 4; ++r) {
        const int b = r0 + r;
        const int g = b >> 6, a = b & 63;
        const float v = (r == 0) ? acc0 : (r == 1) ? acc1 : (r == 2) ? acc2 : acc3;
        int tid2 = (hcol >> 4) * 64 + (g >> 2) * 16 + (hcol & 15);
        z2[(size_t)a * 8192 + (size_t)tid2 * 16 + (g & 3) * 4 + q] = v;
    }
}

// author LSTM on the matrix pipe: ONE block, 512 thr (8 waves).
// Wave wv owns hcols wv*16..+15; gates thread-local (col n = q*128+hcol).
// r_auth in VGPR (16 half8), h fp16 in 2x4KB LDS double buffer, z f32 prefetched.
__global__ __launch_bounds__(512) void k_author2(const _Float16* __restrict__ Afrag,
                                                 const float* __restrict__ z2,
                                                 float* __restrict__ out) {
    __shared__ __align__(16) _Float16 hA[2][2048];

    const int tid = threadIdx.x, lane = tid & 63, wv = tid >> 6;
    const int hl = lane & 15, l4 = lane >> 4;
    const int hcol = wv * 16 + hl;

    half8_t wreg[16];   // [q*4 + kt]
#pragma unroll
    for (int i = 0; i < 16; ++i)
        wreg[i] = *(const half8_t*)&Afrag[(((size_t)(wv * 16 + i)) * 64 + lane) * 8];

    if (tid < 256) *(half8_t*)&hA[0][tid * 8] = (half8_t)(_Float16)0.0f;
    float cst[4] = {0.f, 0.f, 0.f, 0.f};
    float hlast[4] = {0.f, 0.f, 0.f, 0.f};
    __syncthreads();

    const float* zp = &z2[(size_t)tid * 16];
    f32x4 zN[4];
#pragma unroll
    for (int rr = 0; rr < 4; ++rr) zN[rr] = *(const f32x4*)&zp[rr * 4];

    for (int a = 0; a < A_; ++a) {
        const int cur = a & 1, nxt = cur ^ 1;
        f32x4 zv[4];
#pragma unroll
        for (int rr = 0; rr < 4; ++rr) zv[rr] = zN[rr];
        if (a + 1 < A_) {
            const float* zpn = zp + (size_t)(a + 1) * 8192;
#pragma unroll
            for (int rr = 0; rr < 4; ++rr) zN[rr] = *(const f32x4*)&zpn[rr * 4];
        }

        f32x4 acc[4];
#pragma unroll
        for (int i = 0; i < 4; ++i) acc[i] = (f32x4)0.0f;

        if (a > 0) {
#pragma unroll
            for (int kt = 0; kt < 4; ++kt) {
                half8_t ah = *(const half8_t*)&hA[cur][(kt * 64 + lane) * 8];
#pragma unroll
                for (int q = 0; q < 4; ++q)
                    acc[q] = __builtin_amdgcn_mfma_f32_16x16x32_f16(ah, wreg[q * 4 + kt], acc[q], 0, 0, 0);
            }
        }

#pragma unroll
        for (int rr = 0; rr < 4; ++rr) {
            float gi = acc[0][rr] + zv[rr][0];
            float gf = acc[1][rr] + zv[rr][1];
            float gg = acc[2][rr] + zv[rr][2];
            float go = acc[3][rr] + zv[rr][3];
            float cn = sigmoidf_(gf) * cst[rr] + sigmoidf_(gi) * tanhf_(gg);
            cst[rr] = cn;
            float hv = sigmoidf_(go) * tanhf_(cn);
            hlast[rr] = hv;
            int grp = l4 * 4 + rr;
            int lidx = (((hcol >> 5) * 64) + (((hcol & 31) >> 3) * 16 + grp)) * 8 + (hcol & 7);
            hA[nxt][lidx] = (_Float16)hv;
        }
        __syncthreads();
    }

#pragma unroll
    for (int rr = 0; rr < 4; ++rr)
        out[(size_t)(l4 * 4 + rr) * HA_ + hcol] = hlast[rr];
}

// ---------------- launch ----------------
extern "C" void kernel_launch(void* const* d_in, const int* in_sizes, int n_in,
                              void* d_out, int out_size, void* d_ws, size_t ws_size,
                              hipStream_t stream) {
    const float* x       = (const float*)d_in[0];
    const float* w_embed = (const float*)d_in[1];
    const float* b_embed = (const float*)d_in[2];
    const float* k_post  = (const float*)d_in[3];
    const float* r_post  = (const float*)d_in[4];
    const float* b_post  = (const float*)d_in[5];
    const float* k_auth  = (const float*)d_in[6];
    const float* r_auth  = (const float*)d_in[7];
    const float* b_auth  = (const float*)d_in[8];
    float* out = (float*)d_out;

    char* wsb = (char*)d_ws;
    _Float16*       Zq0    = (_Float16*)(wsb);                        // 32 MB
    float*          Bmat   = (float*)(wsb + (32ull << 20));           // 3 MB
    _Float16*       Bt16   = (_Float16*)(wsb + (36ull << 20));        // 1.5 MB
    _Float16*       Bfrag  = (_Float16*)(wsb + (38ull << 20));        // 512 KB
    float*          biasZp = (float*)(wsb + (38ull << 20) + (512ull << 10));  // 4 KB
    _Float16*       Afrag  = (_Float16*)(wsb + (38ull << 20) + (576ull << 10)); // 128 KB
    float*          csave  = (float*)(wsb + (39ull << 20));           // 1 MB
    unsigned short* hsave  = (unsigned short*)(wsb + (40ull << 20));  // 512 KB
    float*          hF32   = (float*)(wsb + (41ull << 20));           // 1 MB
    float*          z2     = (float*)(wsb + (42ull << 20));           // 2 MB
    _Float16*       Zq1    = (_Float16*)(wsb + (44ull << 20));        // 32 MB (overlap only)

    const bool overlap = (ws_size >= (77ull << 20));

    // prep
    k_wk    <<<dim3(N1_ / 256, DIN_ / 4), 256, 0, stream>>>(w_embed, k_post, Bmat);
    k_bias_p<<<dim3(N1_ / 256), 256, 0, stream>>>(b_embed, k_post, b_post, biasZp);
    k_t16   <<<dim3(16, 12), 256, 0, stream>>>(Bmat, Bt16);
    k_bfrag <<<dim3(128), 256, 0, stream>>>(r_post, Bfrag);
    k_afrag <<<dim3(32), 256, 0, stream>>>(r_auth, Afrag);

    // chunk 0 Z
    k_zgemm<<<dim3(512), 1024, 0, stream>>>(x, Bt16, biasZp, Zq0, 0);

    if (overlap) {
        // rec(chunk0) co-scheduled with zgemm(chunk1)
        k_fuse<<<dim3(576), 1024, 0, stream>>>(x, Bt16, biasZp, Zq0, Zq1,
                                               Bfrag, csave, hsave, hF32);
        k_rec <<<dim3(64), 1024, 0, stream>>>(Zq1, Bfrag, csave, hsave, hF32, TCH);
    } else {
        k_rec  <<<dim3(64), 1024, 0, stream>>>(Zq0, Bfrag, csave, hsave, hF32, 0);
        k_zgemm<<<dim3(512), 1024, 0, stream>>>(x, Bt16, biasZp, Zq0, TCH);
        k_rec  <<<dim3(64), 1024, 0, stream>>>(Zq0, Bfrag, csave, hsave, hF32, TCH);
    }

    // author stage
    k_zauth  <<<dim3(N2_ / 256, GA_ / 4), 256, 0, stream>>>(hF32, k_auth, b_auth, z2);
    k_author2<<<dim3(1), 512, 0, stream>>>(Afrag, z2, out);
}

// Round 15
// 337.144 us; speedup vs baseline: 1.1911x; 1.1911x over previous
//
#include <hip/hip_runtime.h>
#include <cstdint>
#include <cstddef>

// dims
#define G_    16
#define A_    64
#define P_    32
#define DIN_  768
#define DEMB_ 384
#define HP_   256
#define HA_   128
#define GA_   1024
#define N1_   1024
#define N2_   512
#define TCH   16          // timesteps per chunk

typedef float    f32x4   __attribute__((ext_vector_type(4)));
typedef _Float16 half8_t __attribute__((ext_vector_type(8)));
typedef _Float16 half4_t __attribute__((ext_vector_type(4)));

__device__ __forceinline__ float sigmoidf_(float x) { return 1.0f / (1.0f + __expf(-x)); }
__device__ __forceinline__ float tanhf_(float x) { return 2.0f / (1.0f + __expf(-2.0f * x)) - 1.0f; }
__device__ __forceinline__ _Float16 us2h(unsigned short u) { _Float16 h; __builtin_memcpy(&h, &u, 2); return h; }
__device__ __forceinline__ unsigned short h2us(_Float16 h) { unsigned short u; __builtin_memcpy(&u, &h, 2); return u; }

// ---------------- prep kernels ----------------

__global__ __launch_bounds__(256) void k_wk(const float* __restrict__ w_embed,
                                            const float* __restrict__ k_post,
                                            float* __restrict__ Bmat) {
    int j  = blockIdx.x * 256 + threadIdx.x;
    int k0 = blockIdx.y * 4;
    float acc0 = 0.f, acc1 = 0.f, acc2 = 0.f, acc3 = 0.f;
    for (int d = 0; d < DEMB_; ++d) {
        float kp = k_post[(size_t)d * N1_ + j];
        acc0 += w_embed[(size_t)(k0 + 0) * DEMB_ + d] * kp;
        acc1 += w_embed[(size_t)(k0 + 1) * DEMB_ + d] * kp;
        acc2 += w_embed[(size_t)(k0 + 2) * DEMB_ + d] * kp;
        acc3 += w_embed[(size_t)(k0 + 3) * DEMB_ + d] * kp;
    }
    Bmat[(size_t)(k0 + 0) * N1_ + j] = acc0;
    Bmat[(size_t)(k0 + 1) * N1_ + j] = acc1;
    Bmat[(size_t)(k0 + 2) * N1_ + j] = acc2;
    Bmat[(size_t)(k0 + 3) * N1_ + j] = acc3;
}

__global__ __launch_bounds__(256) void k_bias_p(const float* __restrict__ b_embed,
                                                const float* __restrict__ k_post,
                                                const float* __restrict__ b_post,
                                                float* __restrict__ biasZp) {
    int p = blockIdx.x * 256 + threadIdx.x;
    int n = (p >> 6) * 16 + (p & 15) + 256 * ((p >> 4) & 3);
    float acc = b_post[n];
    for (int d = 0; d < DEMB_; ++d)
        acc += b_embed[d] * k_post[(size_t)d * N1_ + n];
    biasZp[p] = acc;
}

__global__ __launch_bounds__(256) void k_t16(const float* __restrict__ Bmat,
                                             _Float16* __restrict__ Bt16) {
    __shared__ float tile[64][65];
    const int tid = threadIdx.x;
    const int p0 = blockIdx.x * 64;
    const int k0 = blockIdx.y * 64;
    const int jgrp = p0 >> 6;
#pragma unroll
    for (int i = 0; i < 16; ++i) {
        int idx = i * 256 + tid;
        int pp = idx & 63, kk = idx >> 6;
        int n = jgrp * 16 + (pp & 15) + 256 * ((pp >> 4) & 3);
        tile[pp][kk] = Bmat[(size_t)(k0 + kk) * N1_ + n];
    }
    __syncthreads();
    const int pp = tid >> 2;
    const int kq = (tid & 3) * 16;
    _Float16 buf[16];
#pragma unroll
    for (int i = 0; i < 16; ++i) buf[i] = (_Float16)tile[pp][kq + i];
    _Float16* dst = &Bt16[(size_t)(p0 + pp) * DIN_ + k0 + kq];
    *(half8_t*)dst       = *(half8_t*)&buf[0];
    *(half8_t*)(dst + 8) = *(half8_t*)&buf[8];
}

__global__ __launch_bounds__(256) void k_bfrag(const float* __restrict__ r_post,
                                               _Float16* __restrict__ Bfrag) {
    int idx = blockIdx.x * 256 + threadIdx.x;   // 0..32767
    int pt = idx >> 9;
    int kt = (idx >> 6) & 7;
    int l  = idx & 63;
    int p = pt * 16 + (l & 15);
    int n = (p >> 6) * 16 + (p & 15) + 256 * ((p >> 4) & 3);
    int kb = kt * 32 + (l >> 4) * 8;
    _Float16 buf[8];
#pragma unroll
    for (int s = 0; s < 8; ++s) buf[s] = (_Float16)r_post[(size_t)(kb + s) * N1_ + n];
    *(half8_t*)&Bfrag[(size_t)idx * 8] = *(half8_t*)buf;
}

// ---------------- shared-memory structs ----------------
#define ZBM 128
#define ZBN 256
#define ZBK 32
#define ZPAD 40

struct ZgLDS {
    union {
        struct { _Float16 As[ZBM][ZPAD]; _Float16 Bs[ZBN][ZPAD]; } S;
        _Float16 Hs[64][264];
    } u;
};
struct RecLDS {
    _Float16 wlds[16 * 8 * 64 * 8];   // 128 KB
    _Float16 hbuf[2][4096];           // 16 KB
};

// ---------------- zgemm core: 1024 threads, 128x256 tile ----------------
__device__ __forceinline__ void zgemm_core(ZgLDS* L, int bid, int tid,
                                           const float* __restrict__ x,
                                           const _Float16* __restrict__ Bt16,
                                           const float* __restrict__ biasZp,
                                           _Float16* __restrict__ Zq, int tbase) {
    const int wg = (bid & 7) * 64 + (bid >> 3);   // XCD swizzle (512 % 8 == 0)
    const int bm = (wg & 127) * ZBM;
    const int bn = (wg >> 7) * ZBN;

    const int arow = tid >> 3, akq = (tid & 7) * 4;    // A: 128 rows x 8 quads(4 halfs)
    const int brow = tid >> 2, bkq = (tid & 3) * 8;    // B: 256 rows x 4 octs(8 halfs)
    const int lane = tid & 63, w = tid >> 6;           // w 0..15
    const int wm = (w >> 2) * 32, wn = (w & 3) * 64;
    const int frc = lane & 15, frk = (lane >> 4) * 8;

    const int crow = bm + arow;
    const size_t xrow = (size_t)(crow >> 4) * P_ + tbase + (crow & 15);
    const float*    aptr = &x[xrow * DIN_ + akq];
    const _Float16* bptr = &Bt16[(size_t)(bn + brow) * DIN_ + bkq];

    f32x4 acc[2][4];
#pragma unroll
    for (int i = 0; i < 2; ++i)
#pragma unroll
        for (int j = 0; j < 4; ++j) acc[i][j] = (f32x4)0.0f;

    float4 a0 = *(const float4*)aptr;
    uint4  b0 = *(const uint4*)bptr;

    const int NK = DIN_ / ZBK;   // 24
    for (int kt = 0; kt < NK; ++kt) {
        const int kn = (kt + 1 < NK) ? (kt + 1) * ZBK : kt * ZBK;
        float4 na0 = *(const float4*)(aptr + kn);
        uint4  nb0 = *(const uint4*)(bptr + kn);

        half4_t ahv;
        ahv[0] = (_Float16)a0.x; ahv[1] = (_Float16)a0.y;
        ahv[2] = (_Float16)a0.z; ahv[3] = (_Float16)a0.w;

        __syncthreads();
        *(half4_t*)&L->u.S.As[arow][akq] = ahv;
        *(uint4*)&L->u.S.Bs[brow][bkq]   = b0;
        __syncthreads();

        half8_t bf[4];
#pragma unroll
        for (int fn = 0; fn < 4; ++fn)
            bf[fn] = *(const half8_t*)&L->u.S.Bs[wn + fn * 16 + frc][frk];
#pragma unroll
        for (int fm = 0; fm < 2; ++fm) {
            half8_t aH = *(const half8_t*)&L->u.S.As[wm + fm * 16 + frc][frk];
#pragma unroll
            for (int fn = 0; fn < 4; ++fn)
                acc[fm][fn] = __builtin_amdgcn_mfma_f32_16x16x32_f16(aH, bf[fn], acc[fm][fn], 0, 0, 0);
        }
        a0 = na0; b0 = nb0;
    }

    float bzv[4];
#pragma unroll
    for (int fn = 0; fn < 4; ++fn) bzv[fn] = biasZp[bn + wn + fn * 16 + frc];

#pragma unroll
    for (int half_ = 0; half_ < 2; ++half_) {
        __syncthreads();
        if ((w >> 3) == half_) {
#pragma unroll
            for (int fm = 0; fm < 2; ++fm)
#pragma unroll
                for (int fn = 0; fn < 4; ++fn)
#pragma unroll
                    for (int r = 0; r < 4; ++r) {
                        int rl = ((w >> 2) & 1) * 32 + fm * 16 + (lane >> 4) * 4 + r;
                        int cl = wn + fn * 16 + frc;
                        int clp = ((cl >> 6) * 16 + (cl & 15)) * 4 + ((cl >> 4) & 3);
                        L->u.Hs[rl][clp] = (_Float16)(acc[fm][fn][r] + bzv[fn]);
                    }
        }
        __syncthreads();
        // write Zq2 layout: unit (tloc, hcl); 4 rows x 4 gates = 32B contiguous
        const int brb = (bm + half_ * 64) >> 4;
        const int rg  = brb >> 4;
        const int l4r = (brb & 15) >> 2;
        {
            int tloc = tid >> 6, hcl = tid & 63;
            _Float16 buf[16];
#pragma unroll
            for (int rr = 0; rr < 4; ++rr) {
                half4_t h4 = *(const half4_t*)&L->u.Hs[tloc + 16 * rr][hcl * 4];
                buf[rr * 4 + 0] = h4[0]; buf[rr * 4 + 1] = h4[1];
                buf[rr * 4 + 2] = h4[2]; buf[rr * 4 + 3] = h4[3];
            }
            int wvg  = (bn >> 6) + (hcl >> 4);
            int tid2 = wvg * 64 + l4r * 16 + (hcl & 15);
            _Float16* dst = &Zq[((size_t)(tloc * 64 + rg) * 1024 + tid2) * 16];
            *(uint4*)dst       = *(const uint4*)&buf[0];
            *(uint4*)(dst + 8) = *(const uint4*)&buf[8];
        }
    }
}

// ---------------- rec core: 1024 threads, 16 rows/block, weights 3/4 resident ----------------
__device__ __forceinline__ void rec_core(RecLDS* L, int blk, int tid,
                                         const _Float16* __restrict__ Zq,
                                         const _Float16* __restrict__ Bfrag,
                                         float* __restrict__ csave,
                                         unsigned short* __restrict__ hsave,
                                         float* __restrict__ hF32, int tbase) {
    const int lane = tid & 63, wv = tid >> 6;  // wv 0..15
    const int hl = lane & 15, l4 = lane >> 4;
    const int r0 = blk * 16;
    const int hc = wv * 16 + hl;

    half8_t wreg[16];
#pragma unroll
    for (int q = 0; q < 2; ++q)
#pragma unroll
        for (int kt = 0; kt < 8; ++kt)
            wreg[q * 8 + kt] = *(const half8_t*)&Bfrag[(((size_t)(4 * wv + q) * 8 + kt) * 64 + lane) * 8];
#pragma unroll
    for (int kt = 0; kt < 8; ++kt)
        *(half8_t*)&L->wlds[((wv * 8 + kt) * 64 + lane) * 8] =
            *(const half8_t*)&Bfrag[(((size_t)(4 * wv + 2) * 8 + kt) * 64 + lane) * 8];
    const _Float16* w3base = &Bfrag[((size_t)(4 * wv + 3) * 8 * 64 + lane) * 8];

    float cst[4];
    if (tbase == 0) {
#pragma unroll
        for (int i = 0; i < 4; ++i) cst[i] = 0.f;
    } else {
        f32x4 cv = *(const f32x4*)&csave[((size_t)blk * 1024 + tid) * 4];
#pragma unroll
        for (int i = 0; i < 4; ++i) cst[i] = cv[i];
#pragma unroll
        for (int rr = 0; rr < 4; ++rr) {
            int row = l4 * 4 + rr;
            int lidx = (((hc >> 5) * 64) + (((hc & 31) >> 3) * 16 + row)) * 8 + (hc & 7);
            L->hbuf[0][lidx] = us2h(hsave[((size_t)(r0 + row)) * HP_ + hc]);
        }
    }
    __syncthreads();

    const _Float16* zp0 = &Zq[((size_t)blk * 1024 + tid) * 16];
    half8_t z01N = *(const half8_t*)zp0;
    half8_t z23N = *(const half8_t*)(zp0 + 8);

    for (int tt = 0; tt < TCH; ++tt) {
        const int t = tbase + tt;
        const int cur = t & 1, nxt = cur ^ 1;

        half8_t z01 = z01N, z23 = z23N;
        if (tt + 1 < TCH) {
            const _Float16* zpn = zp0 + (size_t)(tt + 1) * 1048576;
            z01N = *(const half8_t*)zpn;
            z23N = *(const half8_t*)(zpn + 8);
        }

        f32x4 acc[4];
#pragma unroll
        for (int i = 0; i < 4; ++i) acc[i] = (f32x4)0.0f;

        if (t > 0) {
#pragma unroll
            for (int kt = 0; kt < 8; ++kt) {
                half8_t ah = *(const half8_t*)&L->hbuf[cur][(kt * 64 + lane) * 8];
                half8_t b2 = *(const half8_t*)&L->wlds[((wv * 8 + kt) * 64 + lane) * 8];
                half8_t w3 = *(const half8_t*)&w3base[(size_t)kt * 512];
                acc[0] = __builtin_amdgcn_mfma_f32_16x16x32_f16(ah, wreg[kt],     acc[0], 0, 0, 0);
                acc[1] = __builtin_amdgcn_mfma_f32_16x16x32_f16(ah, wreg[8 + kt], acc[1], 0, 0, 0);
                acc[2] = __builtin_amdgcn_mfma_f32_16x16x32_f16(ah, b2,           acc[2], 0, 0, 0);
                acc[3] = __builtin_amdgcn_mfma_f32_16x16x32_f16(ah, w3,           acc[3], 0, 0, 0);
            }
        }

        const bool last = (t == P_ - 1);
        const bool save = (tbase == 0) && (tt == TCH - 1);
#pragma unroll
        for (int rr = 0; rr < 4; ++rr) {
            const half8_t zsrc = (rr < 2) ? z01 : z23;
            const int o = (rr & 1) * 4;
            float gi = acc[0][rr] + (float)zsrc[o + 0];
            float gf = acc[1][rr] + (float)zsrc[o + 1];
            float gg = acc[2][rr] + (float)zsrc[o + 2];
            float go = acc[3][rr] + (float)zsrc[o + 3];
            float cn = sigmoidf_(gf) * cst[rr] + sigmoidf_(gi) * tanhf_(gg);
            cst[rr] = cn;
            float hv = sigmoidf_(go) * tanhf_(cn);
            int row = l4 * 4 + rr;
            int lidx = (((hc >> 5) * 64) + (((hc & 31) >> 3) * 16 + row)) * 8 + (hc & 7);
            _Float16 hh = (_Float16)hv;
            L->hbuf[nxt][lidx] = hh;
            if (save) hsave[((size_t)(r0 + row)) * HP_ + hc] = h2us(hh);
            if (last) hF32[(size_t)(r0 + row) * HP_ + hc] = hv;
        }
        __syncthreads();
    }

    if (tbase == 0) {
        f32x4 cv;
#pragma unroll
        for (int i = 0; i < 4; ++i) cv[i] = cst[i];
        *(f32x4*)&csave[((size_t)blk * 1024 + tid) * 4] = cv;
    }
}

// ---------------- standalone kernels + fused kernel ----------------
__global__ __launch_bounds__(1024, 4) void k_zgemm(const float* __restrict__ x,
                                                   const _Float16* __restrict__ Bt16,
                                                   const float* __restrict__ biasZp,
                                                   _Float16* __restrict__ Zq, int tbase) {
    __shared__ __align__(16) ZgLDS L;
    zgemm_core(&L, blockIdx.x, threadIdx.x, x, Bt16, biasZp, Zq, tbase);
}

__global__ __launch_bounds__(1024, 4) void k_rec(const _Float16* __restrict__ Zq,
                                                 const _Float16* __restrict__ Bfrag,
                                                 float* __restrict__ csave,
                                                 unsigned short* __restrict__ hsave,
                                                 float* __restrict__ hF32, int tbase) {
    __shared__ __align__(16) RecLDS L;
    rec_core(&L, blockIdx.x, threadIdx.x, Zq, Bfrag, csave, hsave, hF32, tbase);
}

// fused: blocks 0..63 = rec(chunk0 from Zq0), blocks 64..575 = zgemm(chunk1 -> Zq1)
__global__ __launch_bounds__(1024, 4) void k_fuse(const float* __restrict__ x,
                                                  const _Float16* __restrict__ Bt16,
                                                  const float* __restrict__ biasZp,
                                                  const _Float16* __restrict__ Zq0,
                                                  _Float16* __restrict__ Zq1,
                                                  const _Float16* __restrict__ Bfrag,
                                                  float* __restrict__ csave,
                                                  unsigned short* __restrict__ hsave,
                                                  float* __restrict__ hF32) {
    __shared__ __align__(16) union { RecLDS r; ZgLDS z; } L;
    if (blockIdx.x < 64)
        rec_core(&L.r, blockIdx.x, threadIdx.x, Zq0, Bfrag, csave, hsave, hF32, 0);
    else
        zgemm_core(&L.z, blockIdx.x - 64, threadIdx.x, x, Bt16, biasZp, Zq1, TCH);
}

// ---------------- author stage (r2-exact structure, measured 65.9 us) ----------------
__global__ __launch_bounds__(256) void k_zauth(const float* __restrict__ h,
                                               const float* __restrict__ k_auth,
                                               const float* __restrict__ b_auth,
                                               float* __restrict__ z_auth) {
    const int j = blockIdx.x * 256 + threadIdx.x;
    const int r0 = blockIdx.y * 4;
    float acc0 = b_auth[j], acc1 = acc0, acc2 = acc0, acc3 = acc0;
    for (int k = 0; k < HP_; ++k) {
        const float kp = k_auth[(size_t)k * N2_ + j];
        acc0 += h[(size_t)(r0 + 0) * HP_ + k] * kp;
        acc1 += h[(size_t)(r0 + 1) * HP_ + k] * kp;
        acc2 += h[(size_t)(r0 + 2) * HP_ + k] * kp;
        acc3 += h[(size_t)(r0 + 3) * HP_ + k] * kp;
    }
#pragma unroll
    for (int r = 0; r < 4; ++r) {
        const int b = r0 + r;
        const int g = b >> 6, a = b & 63;
        const float v = (r == 0) ? acc0 : (r == 1) ? acc1 : (r == 2) ? acc2 : acc3;
        z_auth[((size_t)a * G_ + g) * N2_ + j] = v;
    }
}

// author LSTM: one block per group, 1024 threads; r_auth in registers (64 f32/thread).
__global__ __launch_bounds__(1024) void k_author(const float* __restrict__ z_auth,
                                                 const float* __restrict__ r_auth,
                                                 float* __restrict__ out) {
    const int g = blockIdx.x;
    const int tid = threadIdx.x;
    const int j = tid & 511;
    const int kh = tid >> 9;   // 0 or 1: which half of k

    __shared__ float hs[HA_];
    __shared__ float parts[2][512];

    float rc[64];
#pragma unroll
    for (int kk = 0; kk < 64; ++kk)
        rc[kk] = r_auth[(size_t)(kh * 64 + kk) * N2_ + j];

    float cj = 0.f;
    if (tid < HA_) hs[tid] = 0.f;
    __syncthreads();

    for (int a = 0; a < A_; ++a) {
        float acc = (kh == 0) ? z_auth[((size_t)a * G_ + g) * N2_ + j] : 0.f;
#pragma unroll
        for (int kk = 0; kk < 64; ++kk)
            acc += hs[kh * 64 + kk] * rc[kk];
        parts[kh][j] = acc;
        __syncthreads();
        if (tid < HA_) {
            float gi = parts[0][tid]       + parts[1][tid];
            float gf = parts[0][tid + 128] + parts[1][tid + 128];
            float gg = parts[0][tid + 256] + parts[1][tid + 256];
            float go = parts[0][tid + 384] + parts[1][tid + 384];
            cj = sigmoidf_(gf) * cj + sigmoidf_(gi) * tanhf_(gg);
            hs[tid] = sigmoidf_(go) * tanhf_(cj);
        }
        __syncthreads();
    }
    if (tid < HA_) out[(size_t)g * HA_ + tid] = hs[tid];
}

// ---------------- launch ----------------
extern "C" void kernel_launch(void* const* d_in, const int* in_sizes, int n_in,
                              void* d_out, int out_size, void* d_ws, size_t ws_size,
                              hipStream_t stream) {
    const float* x       = (const float*)d_in[0];
    const float* w_embed = (const float*)d_in[1];
    const float* b_embed = (const float*)d_in[2];
    const float* k_post  = (const float*)d_in[3];
    const float* r_post  = (const float*)d_in[4];
    const float* b_post  = (const float*)d_in[5];
    const float* k_auth  = (const float*)d_in[6];
    const float* r_auth  = (const float*)d_in[7];
    const float* b_auth  = (const float*)d_in[8];
    float* out = (float*)d_out;

    char* wsb = (char*)d_ws;
    _Float16*       Zq0    = (_Float16*)(wsb);                        // 32 MB
    float*          Bmat   = (float*)(wsb + (32ull << 20));           // 3 MB
    _Float16*       Bt16   = (_Float16*)(wsb + (36ull << 20));        // 1.5 MB
    _Float16*       Bfrag  = (_Float16*)(wsb + (38ull << 20));        // 512 KB
    float*          biasZp = (float*)(wsb + (38ull << 20) + (512ull << 10));  // 4 KB
    float*          csave  = (float*)(wsb + (39ull << 20));           // 1 MB
    unsigned short* hsave  = (unsigned short*)(wsb + (40ull << 20));  // 512 KB
    float*          hF32   = (float*)(wsb + (41ull << 20));           // 1 MB
    float*          z_auth = (float*)(wsb + (42ull << 20));           // 2 MB
    _Float16*       Zq1    = (_Float16*)(wsb + (44ull << 20));        // 32 MB (overlap only)

    const bool overlap = (ws_size >= (77ull << 20));

    // prep
    k_wk    <<<dim3(N1_ / 256, DIN_ / 4), 256, 0, stream>>>(w_embed, k_post, Bmat);
    k_bias_p<<<dim3(N1_ / 256), 256, 0, stream>>>(b_embed, k_post, b_post, biasZp);
    k_t16   <<<dim3(16, 12), 256, 0, stream>>>(Bmat, Bt16);
    k_bfrag <<<dim3(128), 256, 0, stream>>>(r_post, Bfrag);

    // chunk 0 Z
    k_zgemm<<<dim3(512), 1024, 0, stream>>>(x, Bt16, biasZp, Zq0, 0);

    if (overlap) {
        // rec(chunk0) co-scheduled with zgemm(chunk1)
        k_fuse<<<dim3(576), 1024, 0, stream>>>(x, Bt16, biasZp, Zq0, Zq1,
                                               Bfrag, csave, hsave, hF32);
        k_rec <<<dim3(64), 1024, 0, stream>>>(Zq1, Bfrag, csave, hsave, hF32, TCH);
    } else {
        k_rec  <<<dim3(64), 1024, 0, stream>>>(Zq0, Bfrag, csave, hsave, hF32, 0);
        k_zgemm<<<dim3(512), 1024, 0, stream>>>(x, Bt16, biasZp, Zq0, TCH);
        k_rec  <<<dim3(64), 1024, 0, stream>>>(Zq0, Bfrag, csave, hsave, hF32, TCH);
    }

    // author stage
    k_zauth <<<dim3(N2_ / 256, GA_ / 4), 256, 0, stream>>>(hF32, k_auth, b_auth, z_auth);
    k_author<<<dim3(G_), 1024, 0, stream>>>(z_auth, r_auth, out);
}